// Round 12
// baseline (243.348 us; speedup 1.0000x reference)
//
#include <hip/hip_runtime.h>
#include <math.h>

// Chained bilinear lookup: out = bilinear(grid0, bilinear(grid1, x)),
// sigmoid per corner sample (both stages).
//
// Shapes: x (N,2) f32; grid1 (U1,U1,2) f32, U1=2080; grid0 (U0,U0,3) f32,
// U0=520; out (N,3) f32.
//
// PRECISION CONTRACT (R0-R22, passing at absmax 3.9e-3 / thr 1.96e-2):
//  - su = x*U must be a SINGLE f32 rounded mul (inline-asm v_mul_f32).
//  - Sigmoid: e = expf(-t) f32, then 1/(1+e) in f64 rounded once.
//    In-query stage-1 sigmoids are value-identical (same fn/order).
//  - f32 blends as written. Re-packing the SAME sigmoided floats into
//    different load shapes is value-identical.
//
// COST MODEL: dur_us = kernels + ~88us FIXED harness overhead.
// LEDGER @R22 (best 237.3): query_rowpair 123.4 (349MB @ 3.30TB/s) +
// rowpair_pack ~22 (104MB @ 4.7TB/s) + sig 4 + 88.
// All tables are L3-resident (g1 34.6MB, rp 69MB, s0 << 256MB L3);
// 3.3-3.54 TB/s = L3 random-64B-line service rate (best observed 3.54).
// Query sits ~25us above pure line-service; in-query sigmoids are FREE
// (R21 packed 113.0 vs R22 rowpair 123.4 == exactly the 37MB byte diff).
// MECHANISMS (measured):
//  - nt STORES on ws tables: query +18us (L3 residency lost, R18). PLAIN.
//  - nt LOADS in query: -41% (R14). NEVER.
//  - vector contiguous loads beat scalar: stage-2 12->4 = -11us (R21).
//  - MLP/thread: null (R19/R20). Stores: 12B/pt wave-contiguous only.
//
// R23 (this): ROWPAIR s0 — s0rp[p][q] = {sig(g0[p][q]), sig(g0[p+1][q])}
//   (24B entry, 6.5MB). Stage-2's 4 corners become 12 CONTIGUOUS floats
//   (48B, ~1.75 lines vs 2) -> 3x f32x4u loads, p1-wrap logic gone.
//   Builder replaces sigmoid_table pass (~4us, same). Predict query
//   116-121, total 229-234. If query moves <=2us: at L3-service
//   roofline -> declare.

typedef float f32x2 __attribute__((ext_vector_type(2)));
typedef float f32x4 __attribute__((ext_vector_type(4)));
typedef float f32x4u __attribute__((ext_vector_type(4), aligned(4)));
typedef float f32x2u __attribute__((ext_vector_type(2), aligned(4)));

__device__ __forceinline__ float mul_rn_nocontract(float a, float b) {
    float r;
    asm("v_mul_f32 %0, %1, %2" : "=v"(r) : "v"(a), "v"(b));
    return r;
}

// ~1-ulp sigmoid matching numpy's f32 chain.
__device__ __forceinline__ float sigmoid_ref(float t) {
    float e = expf(-t);                      // ocml expf, ~1 ulp f32
    return (float)(1.0 / (1.0 + (double)e)); // exact add+div, one rounding
}

// ---- Phase A1: raw row-pair repack of grid1 (PLAIN stores) ----
// rp[u][v] = {g1[u][v].x, .y, g1[u+1 mod U1][v].x, .y}  (16B)
__global__ void __launch_bounds__(256) rowpair_pack_kernel(
    const float* __restrict__ g1, float* __restrict__ rp, int U1)
{
    int v = blockIdx.x * 256 + threadIdx.x;
    int u = blockIdx.y;
    if (v >= U1) return;
    int u1 = u + 1; if (u1 >= U1) u1 = 0;

    const f32x2* g = reinterpret_cast<const f32x2*>(g1);
    f32x2 a = g[(size_t)u  * U1 + v];
    f32x2 b = g[(size_t)u1 * U1 + v];
    f32x4 e;
    e.x = a.x; e.y = a.y; e.z = b.x; e.w = b.y;
    reinterpret_cast<f32x4*>(rp)[(size_t)u * U1 + v] = e;
}

// ---- Phase A2: row-pair sigmoided grid0 ----
// s0rp[p][q] = {sig(g0[p][q].rgb), sig(g0[p+1 mod U0][q].rgb)} (24B)
// Replaces the flat sigmoid_table pass; p-wrap is baked into the table.
__global__ void __launch_bounds__(256) s0rp_pack_kernel(
    const float* __restrict__ g0, float* __restrict__ s0rp, int U0)
{
    int q = blockIdx.x * 256 + threadIdx.x;
    int p = blockIdx.y;
    if (q >= U0) return;
    int p1 = p + 1; if (p1 >= U0) p1 = 0;

    const float* t0 = g0 + (size_t)(p  * U0 + q) * 3;
    const float* t1 = g0 + (size_t)(p1 * U0 + q) * 3;
    float* o = s0rp + (size_t)(p * U0 + q) * 6;
    f32x4u w0;
    f32x2u w1;
    w0.x = sigmoid_ref(t0[0]); w0.y = sigmoid_ref(t0[1]);
    w0.z = sigmoid_ref(t0[2]); w0.w = sigmoid_ref(t1[0]);
    w1.x = sigmoid_ref(t1[1]); w1.y = sigmoid_ref(t1[2]);
    *reinterpret_cast<f32x4u*>(o) = w0;
    *reinterpret_cast<f32x2u*>(o + 4) = w1;
}

// ---- legacy Phase A2 (flat sigmoid table) for fallback paths ----
__global__ void __launch_bounds__(256) sigmoid_table_kernel(
    const float4* __restrict__ in, float4* __restrict__ out, int n4)
{
    int i = blockIdx.x * blockDim.x + threadIdx.x;
    if (i >= n4) return;
    float4 v = in[i];
    float4 r;
    r.x = sigmoid_ref(v.x);
    r.y = sigmoid_ref(v.y);
    r.z = sigmoid_ref(v.z);
    r.w = sigmoid_ref(v.w);
    out[i] = r;
}

// ---- Phase B: rowpair query; stage-2 via s0rp (12 contiguous floats) ----
__global__ void __launch_bounds__(256) query_rowpair_kernel(
    const float* __restrict__ x,
    const float* __restrict__ rp,    // row-pair raw grid1, U1*U1*4 floats
    const float* __restrict__ s0rp,  // row-pair sigmoided grid0, U0*U0*6
    float* __restrict__ out,         // (N,3)
    int N, int U1, int U0)
{
    int i = blockIdx.x * blockDim.x + threadIdx.x;
    if (i >= N) return;

    f32x2 uv = __builtin_nontemporal_load(
        reinterpret_cast<const f32x2*>(x) + i);

    // stage-1 coords: single rounded f32 mul (contract-proof)
    float fU1 = (float)U1;
    float su = mul_rn_nocontract(uv.x, fU1);
    float sv = mul_rn_nocontract(uv.y, fU1);
    float u0f = floorf(su), v0f = floorf(sv);
    float fu = su - u0f;              // exact
    float fv = sv - v0f;
    int u0 = (int)u0f % U1; if (u0 < 0) u0 += U1;
    int v0 = (int)v0f % U1; if (v0 < 0) v0 += U1;
    int v1 = v0 + 1; if (v1 >= U1) v1 = 0;

    // two adjacent 16B entries; PLAIN loads (R14); rp L3-resident (R18)
    const f32x4* rpv = reinterpret_cast<const f32x4*>(rp)
                     + (size_t)u0 * U1;
    f32x4 e0 = rpv[v0];   // t00.xy | t10.xy
    f32x4 e1 = rpv[v1];   // t01.xy | t11.xy

    // stage-1 sigmoids in-kernel (hidden under memory latency, R22)
    float a00x = sigmoid_ref(e0.x), a00y = sigmoid_ref(e0.y);
    float a10x = sigmoid_ref(e0.z), a10y = sigmoid_ref(e0.w);
    float a01x = sigmoid_ref(e1.x), a01y = sigmoid_ref(e1.y);
    float a11x = sigmoid_ref(e1.z), a11y = sigmoid_ref(e1.w);

    float omfu = 1.0f - fu, omfv = 1.0f - fv;
    float kx = (a00x * omfu + a10x * fu) * omfv
             + (a01x * omfu + a11x * fu) * fv;
    float ky = (a00y * omfu + a10y * fu) * omfv
             + (a01y * omfu + a11y * fu) * fv;

    // stage-2 coords
    float fU0 = (float)U0;
    float su2 = mul_rn_nocontract(kx, fU0);
    float sv2 = mul_rn_nocontract(ky, fU0);
    float u0f2 = floorf(su2), v0f2 = floorf(sv2);
    float fu2 = su2 - u0f2, fv2 = sv2 - v0f2;
    int p0 = (int)u0f2 % U0; if (p0 < 0) p0 += U0;
    int q0 = (int)v0f2 % U0; if (q0 < 0) q0 += U0;
    int q1 = q0 + 1; if (q1 >= U0) q1 = 0;

    // stage-2 corners: s0rp entries (p0,q0),(p0,q1) = 12 contiguous
    // floats when q1==q0+1 (99.8%): 3x f32x4u loads (~1.75 lines).
    // p-wrap is baked into the table. Wrap lanes (q1==0): 2 entry loads.
    float a00, a01, a02, b00v, b01v, b02v;   // texels (p0,q0),(p1,q0)
    float a10, a11, a12, b10v, b11v, b12v;   // texels (p0,q1),(p1,q1)
    if (q1 != 0) {
        const float* bp = s0rp + (size_t)(p0 * U0 + q0) * 6;
        f32x4u h0 = *reinterpret_cast<const f32x4u*>(bp);
        f32x4u h1 = *reinterpret_cast<const f32x4u*>(bp + 4);
        f32x4u h2 = *reinterpret_cast<const f32x4u*>(bp + 8);
        a00 = h0.x; a01 = h0.y; a02 = h0.z;
        b00v = h0.w; b01v = h1.x; b02v = h1.y;
        a10 = h1.z; a11 = h1.w; a12 = h2.x;
        b10v = h2.y; b11v = h2.z; b12v = h2.w;
    } else {
        const float* bp0 = s0rp + (size_t)(p0 * U0 + q0) * 6;
        f32x4u h0 = *reinterpret_cast<const f32x4u*>(bp0);
        f32x2u h1 = *reinterpret_cast<const f32x2u*>(bp0 + 4);
        a00 = h0.x; a01 = h0.y; a02 = h0.z;
        b00v = h0.w; b01v = h1.x; b02v = h1.y;
        const float* bp1 = s0rp + (size_t)(p0 * U0 + q1) * 6;
        f32x4u h2 = *reinterpret_cast<const f32x4u*>(bp1);
        f32x2u h3 = *reinterpret_cast<const f32x2u*>(bp1 + 4);
        a10 = h2.x; a11 = h2.y; a12 = h2.z;
        b10v = h2.w; b11v = h3.x; b12v = h3.y;
    }

    // blends: identical arithmetic/order to the validated form
    float omfu2 = 1.0f - fu2, omfv2 = 1.0f - fv2;
    float r0 = (a00 * omfu2 + b00v * fu2) * omfv2
             + (a10 * omfu2 + b10v * fu2) * fv2;
    float r1 = (a01 * omfu2 + b01v * fu2) * omfv2
             + (a11 * omfu2 + b11v * fu2) * fv2;
    float r2 = (a02 * omfu2 + b02v * fu2) * omfv2
             + (a12 * omfu2 + b12v * fu2) * fv2;
    out[3*i+0] = r0; out[3*i+1] = r1; out[3*i+2] = r2;
}

// ---- Middle variant: direct query, no grid1 pre-pass (R17, 197us) ----
__global__ void __launch_bounds__(256) query_direct_kernel(
    const float* __restrict__ x,
    const float* __restrict__ g1,
    const float* __restrict__ s0,
    float* __restrict__ out,
    int N, int U1, int U0)
{
    int i = blockIdx.x * blockDim.x + threadIdx.x;
    if (i >= N) return;

    f32x2 uv = __builtin_nontemporal_load(
        reinterpret_cast<const f32x2*>(x) + i);

    float fU1 = (float)U1;
    float su = mul_rn_nocontract(uv.x, fU1);
    float sv = mul_rn_nocontract(uv.y, fU1);
    float u0f = floorf(su), v0f = floorf(sv);
    float fu = su - u0f, fv = sv - v0f;
    int u0 = (int)u0f % U1; if (u0 < 0) u0 += U1;
    int v0 = (int)v0f % U1; if (v0 < 0) v0 += U1;
    int u1 = u0 + 1; if (u1 >= U1) u1 = 0;
    int v1 = v0 + 1; if (v1 >= U1) v1 = 0;

    const f32x2* g = reinterpret_cast<const f32x2*>(g1);
    const f32x2* row0 = g + (size_t)u0 * U1;
    const f32x2* row1 = g + (size_t)u1 * U1;
    f32x2 t00 = row0[v0];
    f32x2 t01 = row0[v1];
    f32x2 t10 = row1[v0];
    f32x2 t11 = row1[v1];

    float a00x = sigmoid_ref(t00.x), a00y = sigmoid_ref(t00.y);
    float a10x = sigmoid_ref(t10.x), a10y = sigmoid_ref(t10.y);
    float a01x = sigmoid_ref(t01.x), a01y = sigmoid_ref(t01.y);
    float a11x = sigmoid_ref(t11.x), a11y = sigmoid_ref(t11.y);

    float omfu = 1.0f - fu, omfv = 1.0f - fv;
    float kx = (a00x * omfu + a10x * fu) * omfv
             + (a01x * omfu + a11x * fu) * fv;
    float ky = (a00y * omfu + a10y * fu) * omfv
             + (a01y * omfu + a11y * fu) * fv;

    float fU0 = (float)U0;
    float su2 = mul_rn_nocontract(kx, fU0);
    float sv2 = mul_rn_nocontract(ky, fU0);
    float u0f2 = floorf(su2), v0f2 = floorf(sv2);
    float fu2 = su2 - u0f2, fv2 = sv2 - v0f2;
    int p0 = (int)u0f2 % U0; if (p0 < 0) p0 += U0;
    int q0 = (int)v0f2 % U0; if (q0 < 0) q0 += U0;
    int p1 = p0 + 1; if (p1 >= U0) p1 = 0;
    int q1 = q0 + 1; if (q1 >= U0) q1 = 0;
    int b00 = (p0 * U0 + q0) * 3, b10 = (p1 * U0 + q0) * 3;
    int b01 = (p0 * U0 + q1) * 3, b11 = (p1 * U0 + q1) * 3;
    float omfu2 = 1.0f - fu2, omfv2 = 1.0f - fv2;
    float r0 = (s0[b00+0] * omfu2 + s0[b10+0] * fu2) * omfv2
             + (s0[b01+0] * omfu2 + s0[b11+0] * fu2) * fv2;
    float r1 = (s0[b00+1] * omfu2 + s0[b10+1] * fu2) * omfv2
             + (s0[b01+1] * omfu2 + s0[b11+1] * fu2) * fv2;
    float r2 = (s0[b00+2] * omfu2 + s0[b10+2] * fu2) * omfv2
             + (s0[b01+2] * omfu2 + s0[b11+2] * fu2) * fv2;
    out[3*i+0] = r0; out[3*i+1] = r1; out[3*i+2] = r2;
}

// ---- Full fallback: all sigmoids in-kernel (ws too small) ----
__global__ void __launch_bounds__(256) query_kernel_fallback(
    const float* __restrict__ x,
    const float* __restrict__ g1,
    const float* __restrict__ g0,
    float* __restrict__ out,
    int N, int U1, int U0)
{
    int i = blockIdx.x * blockDim.x + threadIdx.x;
    if (i >= N) return;
    float2 uv = reinterpret_cast<const float2*>(x)[i];
    float fU1 = (float)U1;
    float su = mul_rn_nocontract(uv.x, fU1);
    float sv = mul_rn_nocontract(uv.y, fU1);
    float u0f = floorf(su), v0f = floorf(sv);
    float fu = su - u0f, fv = sv - v0f;
    int u0 = (int)u0f % U1; if (u0 < 0) u0 += U1;
    int v0 = (int)v0f % U1; if (v0 < 0) v0 += U1;
    int u1 = u0 + 1; if (u1 >= U1) u1 = 0;
    int v1 = v0 + 1; if (v1 >= U1) v1 = 0;
    const float2* g1v = reinterpret_cast<const float2*>(g1);
    float2 t00 = g1v[u0 * U1 + v0];
    float2 t10 = g1v[u1 * U1 + v0];
    float2 t01 = g1v[u0 * U1 + v1];
    float2 t11 = g1v[u1 * U1 + v1];
    float a00x = sigmoid_ref(t00.x), a00y = sigmoid_ref(t00.y);
    float a10x = sigmoid_ref(t10.x), a10y = sigmoid_ref(t10.y);
    float a01x = sigmoid_ref(t01.x), a01y = sigmoid_ref(t01.y);
    float a11x = sigmoid_ref(t11.x), a11y = sigmoid_ref(t11.y);
    float omfu = 1.0f - fu, omfv = 1.0f - fv;
    float kx = (a00x * omfu + a10x * fu) * omfv + (a01x * omfu + a11x * fu) * fv;
    float ky = (a00y * omfu + a10y * fu) * omfv + (a01y * omfu + a11y * fu) * fv;
    float fU0 = (float)U0;
    float su2 = mul_rn_nocontract(kx, fU0);
    float sv2 = mul_rn_nocontract(ky, fU0);
    float u0f2 = floorf(su2), v0f2 = floorf(sv2);
    float fu2 = su2 - u0f2, fv2 = sv2 - v0f2;
    int p0 = (int)u0f2 % U0; if (p0 < 0) p0 += U0;
    int q0 = (int)v0f2 % U0; if (q0 < 0) q0 += U0;
    int p1 = p0 + 1; if (p1 >= U0) p1 = 0;
    int q1 = q0 + 1; if (q1 >= U0) q1 = 0;
    int b00 = (p0 * U0 + q0) * 3, b10 = (p1 * U0 + q0) * 3;
    int b01 = (p0 * U0 + q1) * 3, b11 = (p1 * U0 + q1) * 3;
    float omfu2 = 1.0f - fu2, omfv2 = 1.0f - fv2;
    float r0 = (sigmoid_ref(g0[b00+0]) * omfu2 + sigmoid_ref(g0[b10+0]) * fu2) * omfv2
             + (sigmoid_ref(g0[b01+0]) * omfu2 + sigmoid_ref(g0[b11+0]) * fu2) * fv2;
    float r1 = (sigmoid_ref(g0[b00+1]) * omfu2 + sigmoid_ref(g0[b10+1]) * fu2) * omfv2
             + (sigmoid_ref(g0[b01+1]) * omfu2 + sigmoid_ref(g0[b11+1]) * fu2) * fv2;
    float r2 = (sigmoid_ref(g0[b00+2]) * omfu2 + sigmoid_ref(g0[b10+2]) * fu2) * omfv2
             + (sigmoid_ref(g0[b01+2]) * omfu2 + sigmoid_ref(g0[b11+2]) * fu2) * fv2;
    out[3*i+0] = r0; out[3*i+1] = r1; out[3*i+2] = r2;
}

extern "C" void kernel_launch(void* const* d_in, const int* in_sizes, int n_in,
                              void* d_out, int out_size, void* d_ws, size_t ws_size,
                              hipStream_t stream) {
    const float* x  = (const float*)d_in[0];
    const float* g1 = (const float*)d_in[1];
    const float* g0 = (const float*)d_in[2];
    float* out = (float*)d_out;

    int N = in_sizes[0] / 2;
    long long n1 = in_sizes[1];          // U1*U1*2
    long long n0 = in_sizes[2];          // U0*U0*3
    int U1 = (int)(sqrt((double)(n1 / 2)) + 0.5);
    int U0 = (int)(sqrt((double)(n0 / 3)) + 0.5);
    long long ncells1 = (long long)U1 * U1;

    int block = 256;
    size_t need_rowpair = ((size_t)ncells1 * 4 + (size_t)n0 * 2) * sizeof(float);
    size_t need_s0      = (size_t)n0 * sizeof(float);

    if (ws_size >= need_rowpair) {
        float* rp   = (float*)d_ws;                   // 69.2 MB row-pair g1
        float* s0rp = rp + ncells1 * 4;               // 6.5 MB row-pair s0
        dim3 pgrid((U1 + block - 1) / block, U1);
        rowpair_pack_kernel<<<pgrid, block, 0, stream>>>(g1, rp, U1);
        dim3 sgrid((U0 + block - 1) / block, U0);
        s0rp_pack_kernel<<<sgrid, block, 0, stream>>>(g0, s0rp, U0);
        query_rowpair_kernel<<<(N + block - 1) / block, block, 0, stream>>>(
            x, rp, s0rp, out, N, U1, U0);
    } else if (ws_size >= need_s0 && (n0 % 4) == 0) {
        float* s0 = (float*)d_ws;                     // 3.2 MB sigmoided g0
        int n0_4 = (int)(n0 / 4);
        sigmoid_table_kernel<<<(n0_4 + block - 1) / block, block, 0, stream>>>(
            (const float4*)g0, (float4*)s0, n0_4);
        query_direct_kernel<<<(N + block - 1) / block, block, 0, stream>>>(
            x, g1, s0, out, N, U1, U0);
    } else {
        query_kernel_fallback<<<(N + block - 1) / block, block, 0, stream>>>(
            x, g1, g0, out, N, U1, U0);
    }
}

// Round 13
// 238.192 us; speedup vs baseline: 1.0216x; 1.0216x over previous
//
#include <hip/hip_runtime.h>
#include <math.h>

// Chained bilinear lookup: out = bilinear(grid0, bilinear(grid1, x)),
// sigmoid per corner sample (both stages).
//
// Shapes: x (N,2) f32; grid1 (U1,U1,2) f32, U1=2080; grid0 (U0,U0,3) f32,
// U0=520; out (N,3) f32.
//
// PRECISION CONTRACT (R0-R23, passing at absmax 3.9e-3 / thr 1.96e-2):
//  - su = x*U must be a SINGLE f32 rounded mul (inline-asm v_mul_f32).
//  - Sigmoid: e = expf(-t) f32, then 1/(1+e) in f64 rounded once.
//    In-query stage-1 sigmoids are value-identical (same fn/order).
//  - f32 blends as written. Load-shape changes on the same floats are
//    value-identical.
//
// COST MODEL: dur_us = kernels + ~88us FIXED harness overhead
// (invariant across ws size / kernel count; R17 vs R22).
// LEDGER @R22 (BEST 237.3): query_rowpair 123.4 (349MB @ 3.3TB/s) +
// rowpair_pack 22 (104MB @ 4.7TB/s) + sig 4 + 88.
// MECHANISMS (all measured, session A/Bs):
//  - nt STORES on ws tables: query +18us (L3 residency lost, R18). PLAIN.
//  - nt LOADS in query: -41% (R14). NEVER.
//  - vector contiguous loads beat scalar (stage-2 12->4: -11us, R21).
//  - MLP/thread: null (R19/R20). Stores: 12B/pt wave-contiguous (R19).
//  - R23: s0 table MUST stay < 4MB per-XCD L2: doubling it to 6.5MB
//    (rowpair s0) added +53MB FETCH (+4us) — L2-residency of the hot
//    stage-2 table beats halving its load count. Flat 3.2MB s0 wins.
//  - Packed-cell (64B/pt query, R21): query -10.4 but pack +22.6. Net
//    loss vs rowpair.
// FLOOR ESTIMATE: ~224us (query @ best-observed 3.63TB/s service +
// pack @ stream + 88). Current 237.3 is within ~6% with no identified
// mechanism to close it. R24 = revert to R22 exact; if confirmed,
// declare roofline.

typedef float f32x2 __attribute__((ext_vector_type(2)));
typedef float f32x4 __attribute__((ext_vector_type(4)));
typedef float f32x4u __attribute__((ext_vector_type(4), aligned(4)));
typedef float f32x2u __attribute__((ext_vector_type(2), aligned(4)));

__device__ __forceinline__ float mul_rn_nocontract(float a, float b) {
    float r;
    asm("v_mul_f32 %0, %1, %2" : "=v"(r) : "v"(a), "v"(b));
    return r;
}

// ~1-ulp sigmoid matching numpy's f32 chain.
__device__ __forceinline__ float sigmoid_ref(float t) {
    float e = expf(-t);                      // ocml expf, ~1 ulp f32
    return (float)(1.0 / (1.0 + (double)e)); // exact add+div, one rounding
}

// ---- Phase A1: raw row-pair repack of grid1 (PLAIN stores) ----
// rp[u][v] = {g1[u][v].x, .y, g1[u+1 mod U1][v].x, .y}  (16B)
__global__ void __launch_bounds__(256) rowpair_pack_kernel(
    const float* __restrict__ g1, float* __restrict__ rp, int U1)
{
    int v = blockIdx.x * 256 + threadIdx.x;
    int u = blockIdx.y;
    if (v >= U1) return;
    int u1 = u + 1; if (u1 >= U1) u1 = 0;

    const f32x2* g = reinterpret_cast<const f32x2*>(g1);
    f32x2 a = g[(size_t)u  * U1 + v];
    f32x2 b = g[(size_t)u1 * U1 + v];
    f32x4 e;
    e.x = a.x; e.y = a.y; e.z = b.x; e.w = b.y;
    reinterpret_cast<f32x4*>(rp)[(size_t)u * U1 + v] = e;
}

// ---- Phase A2: elementwise sigmoid of a table (float4-vectorized) ----
// Output s0 is 3.2MB: per-XCD L2-resident (R23: do NOT enlarge).
__global__ void __launch_bounds__(256) sigmoid_table_kernel(
    const float4* __restrict__ in, float4* __restrict__ out, int n4)
{
    int i = blockIdx.x * blockDim.x + threadIdx.x;
    if (i >= n4) return;
    float4 v = in[i];
    float4 r;
    r.x = sigmoid_ref(v.x);
    r.y = sigmoid_ref(v.y);
    r.z = sigmoid_ref(v.z);
    r.w = sigmoid_ref(v.w);
    out[i] = r;
}

// ---- Phase B: rowpair query, in-kernel stage-1 sigmoids, vector stage-2 ----
__global__ void __launch_bounds__(256) query_rowpair_kernel(
    const float* __restrict__ x,
    const float* __restrict__ rp,   // row-pair raw corners, U1*U1*4 floats
    const float* __restrict__ s0,   // sigmoid(grid0), (U0,U0,3), L2-resident
    float* __restrict__ out,        // (N,3)
    int N, int U1, int U0)
{
    int i = blockIdx.x * blockDim.x + threadIdx.x;
    if (i >= N) return;

    f32x2 uv = __builtin_nontemporal_load(
        reinterpret_cast<const f32x2*>(x) + i);

    // stage-1 coords: single rounded f32 mul (contract-proof)
    float fU1 = (float)U1;
    float su = mul_rn_nocontract(uv.x, fU1);
    float sv = mul_rn_nocontract(uv.y, fU1);
    float u0f = floorf(su), v0f = floorf(sv);
    float fu = su - u0f;              // exact
    float fv = sv - v0f;
    int u0 = (int)u0f % U1; if (u0 < 0) u0 += U1;
    int v0 = (int)v0f % U1; if (v0 < 0) v0 += U1;
    int v1 = v0 + 1; if (v1 >= U1) v1 = 0;

    // two adjacent 16B entries (32B span, 1 line 75% / 2 lines 25%);
    // PLAIN loads (R14); rp is L3-resident (plain-stored, R18)
    const f32x4* rpv = reinterpret_cast<const f32x4*>(rp)
                     + (size_t)u0 * U1;
    f32x4 e0 = rpv[v0];   // t00.xy | t10.xy
    f32x4 e1 = rpv[v1];   // t01.xy | t11.xy

    // stage-1 sigmoids in-kernel (hidden under memory latency, R22)
    float a00x = sigmoid_ref(e0.x), a00y = sigmoid_ref(e0.y);
    float a10x = sigmoid_ref(e0.z), a10y = sigmoid_ref(e0.w);
    float a01x = sigmoid_ref(e1.x), a01y = sigmoid_ref(e1.y);
    float a11x = sigmoid_ref(e1.z), a11y = sigmoid_ref(e1.w);

    float omfu = 1.0f - fu, omfv = 1.0f - fv;
    float kx = (a00x * omfu + a10x * fu) * omfv
             + (a01x * omfu + a11x * fu) * fv;
    float ky = (a00y * omfu + a10y * fu) * omfv
             + (a01y * omfu + a11y * fu) * fv;

    // stage-2 coords
    float fU0 = (float)U0;
    float su2 = mul_rn_nocontract(kx, fU0);
    float sv2 = mul_rn_nocontract(ky, fU0);
    float u0f2 = floorf(su2), v0f2 = floorf(sv2);
    float fu2 = su2 - u0f2, fv2 = sv2 - v0f2;
    int p0 = (int)u0f2 % U0; if (p0 < 0) p0 += U0;
    int q0 = (int)v0f2 % U0; if (q0 < 0) q0 += U0;
    int p1 = p0 + 1; if (p1 >= U0) p1 = 0;
    int q1 = q0 + 1; if (q1 >= U0) q1 = 0;

    // stage-2 corner fetch: 6 contiguous floats per row when q1==q0+1
    // (99.8%): align-4 f32x4 + f32x2 per row = 4 loads not 12 (R21,
    // -11us). Same floats, same lines, same blend order. Wrap lanes
    // (q1==0) take the scalar path. s0 is L2-resident (3.2MB < 4MB).
    float a00, a01, a02, a10, a11, a12;       // row p0: texel q0 | q1
    float b00v, b01v, b02v, b10v, b11v, b12v; // row p1
    if (q1 != 0) {
        const float* r0p = s0 + (size_t)(p0 * U0 + q0) * 3;
        f32x4u h0 = *reinterpret_cast<const f32x4u*>(r0p);
        f32x2u h1 = *reinterpret_cast<const f32x2u*>(r0p + 4);
        a00 = h0.x; a01 = h0.y; a02 = h0.z;
        a10 = h0.w; a11 = h1.x; a12 = h1.y;
        const float* r1p = s0 + (size_t)(p1 * U0 + q0) * 3;
        f32x4u h2 = *reinterpret_cast<const f32x4u*>(r1p);
        f32x2u h3 = *reinterpret_cast<const f32x2u*>(r1p + 4);
        b00v = h2.x; b01v = h2.y; b02v = h2.z;
        b10v = h3.x; b11v = h3.y; b12v = h2.w;
        // NOTE: careful mapping below — use explicit fields:
        b00v = h2.x; b01v = h2.y; b02v = h2.z;
        b10v = h2.w; b11v = h3.x; b12v = h3.y;
    } else {
        int c00 = (p0 * U0 + q0) * 3, c01 = (p0 * U0 + q1) * 3;
        int c10 = (p1 * U0 + q0) * 3, c11 = (p1 * U0 + q1) * 3;
        a00 = s0[c00+0]; a01 = s0[c00+1]; a02 = s0[c00+2];
        a10 = s0[c01+0]; a11 = s0[c01+1]; a12 = s0[c01+2];
        b00v = s0[c10+0]; b01v = s0[c10+1]; b02v = s0[c10+2];
        b10v = s0[c11+0]; b11v = s0[c11+1]; b12v = s0[c11+2];
    }

    float omfu2 = 1.0f - fu2, omfv2 = 1.0f - fv2;
    float r0 = (a00 * omfu2 + b00v * fu2) * omfv2
             + (a10 * omfu2 + b10v * fu2) * fv2;
    float r1 = (a01 * omfu2 + b01v * fu2) * omfv2
             + (a11 * omfu2 + b11v * fu2) * fv2;
    float r2 = (a02 * omfu2 + b02v * fu2) * omfv2
             + (a12 * omfu2 + b12v * fu2) * fv2;
    out[3*i+0] = r0; out[3*i+1] = r1; out[3*i+2] = r2;
}

// ---- Middle variant: direct query, no grid1 pre-pass (R17, 197us) ----
__global__ void __launch_bounds__(256) query_direct_kernel(
    const float* __restrict__ x,
    const float* __restrict__ g1,
    const float* __restrict__ s0,
    float* __restrict__ out,
    int N, int U1, int U0)
{
    int i = blockIdx.x * blockDim.x + threadIdx.x;
    if (i >= N) return;

    f32x2 uv = __builtin_nontemporal_load(
        reinterpret_cast<const f32x2*>(x) + i);

    float fU1 = (float)U1;
    float su = mul_rn_nocontract(uv.x, fU1);
    float sv = mul_rn_nocontract(uv.y, fU1);
    float u0f = floorf(su), v0f = floorf(sv);
    float fu = su - u0f, fv = sv - v0f;
    int u0 = (int)u0f % U1; if (u0 < 0) u0 += U1;
    int v0 = (int)v0f % U1; if (v0 < 0) v0 += U1;
    int u1 = u0 + 1; if (u1 >= U1) u1 = 0;
    int v1 = v0 + 1; if (v1 >= U1) v1 = 0;

    const f32x2* g = reinterpret_cast<const f32x2*>(g1);
    const f32x2* row0 = g + (size_t)u0 * U1;
    const f32x2* row1 = g + (size_t)u1 * U1;
    f32x2 t00 = row0[v0];
    f32x2 t01 = row0[v1];
    f32x2 t10 = row1[v0];
    f32x2 t11 = row1[v1];

    float a00x = sigmoid_ref(t00.x), a00y = sigmoid_ref(t00.y);
    float a10x = sigmoid_ref(t10.x), a10y = sigmoid_ref(t10.y);
    float a01x = sigmoid_ref(t01.x), a01y = sigmoid_ref(t01.y);
    float a11x = sigmoid_ref(t11.x), a11y = sigmoid_ref(t11.y);

    float omfu = 1.0f - fu, omfv = 1.0f - fv;
    float kx = (a00x * omfu + a10x * fu) * omfv
             + (a01x * omfu + a11x * fu) * fv;
    float ky = (a00y * omfu + a10y * fu) * omfv
             + (a01y * omfu + a11y * fu) * fv;

    float fU0 = (float)U0;
    float su2 = mul_rn_nocontract(kx, fU0);
    float sv2 = mul_rn_nocontract(ky, fU0);
    float u0f2 = floorf(su2), v0f2 = floorf(sv2);
    float fu2 = su2 - u0f2, fv2 = sv2 - v0f2;
    int p0 = (int)u0f2 % U0; if (p0 < 0) p0 += U0;
    int q0 = (int)v0f2 % U0; if (q0 < 0) q0 += U0;
    int p1 = p0 + 1; if (p1 >= U0) p1 = 0;
    int q1 = q0 + 1; if (q1 >= U0) q1 = 0;
    int b00 = (p0 * U0 + q0) * 3, b10 = (p1 * U0 + q0) * 3;
    int b01 = (p0 * U0 + q1) * 3, b11 = (p1 * U0 + q1) * 3;
    float omfu2 = 1.0f - fu2, omfv2 = 1.0f - fv2;
    float r0 = (s0[b00+0] * omfu2 + s0[b10+0] * fu2) * omfv2
             + (s0[b01+0] * omfu2 + s0[b11+0] * fu2) * fv2;
    float r1 = (s0[b00+1] * omfu2 + s0[b10+1] * fu2) * omfv2
             + (s0[b01+1] * omfu2 + s0[b11+1] * fu2) * fv2;
    float r2 = (s0[b00+2] * omfu2 + s0[b10+2] * fu2) * omfv2
             + (s0[b01+2] * omfu2 + s0[b11+2] * fu2) * fv2;
    out[3*i+0] = r0; out[3*i+1] = r1; out[3*i+2] = r2;
}

// ---- Full fallback: all sigmoids in-kernel (ws too small) ----
__global__ void __launch_bounds__(256) query_kernel_fallback(
    const float* __restrict__ x,
    const float* __restrict__ g1,
    const float* __restrict__ g0,
    float* __restrict__ out,
    int N, int U1, int U0)
{
    int i = blockIdx.x * blockDim.x + threadIdx.x;
    if (i >= N) return;
    float2 uv = reinterpret_cast<const float2*>(x)[i];
    float fU1 = (float)U1;
    float su = mul_rn_nocontract(uv.x, fU1);
    float sv = mul_rn_nocontract(uv.y, fU1);
    float u0f = floorf(su), v0f = floorf(sv);
    float fu = su - u0f, fv = sv - v0f;
    int u0 = (int)u0f % U1; if (u0 < 0) u0 += U1;
    int v0 = (int)v0f % U1; if (v0 < 0) v0 += U1;
    int u1 = u0 + 1; if (u1 >= U1) u1 = 0;
    int v1 = v0 + 1; if (v1 >= U1) v1 = 0;
    const float2* g1v = reinterpret_cast<const float2*>(g1);
    float2 t00 = g1v[u0 * U1 + v0];
    float2 t10 = g1v[u1 * U1 + v0];
    float2 t01 = g1v[u0 * U1 + v1];
    float2 t11 = g1v[u1 * U1 + v1];
    float a00x = sigmoid_ref(t00.x), a00y = sigmoid_ref(t00.y);
    float a10x = sigmoid_ref(t10.x), a10y = sigmoid_ref(t10.y);
    float a01x = sigmoid_ref(t01.x), a01y = sigmoid_ref(t01.y);
    float a11x = sigmoid_ref(t11.x), a11y = sigmoid_ref(t11.y);
    float omfu = 1.0f - fu, omfv = 1.0f - fv;
    float kx = (a00x * omfu + a10x * fu) * omfv + (a01x * omfu + a11x * fu) * fv;
    float ky = (a00y * omfu + a10y * fu) * omfv + (a01y * omfu + a11y * fu) * fv;
    float fU0 = (float)U0;
    float su2 = mul_rn_nocontract(kx, fU0);
    float sv2 = mul_rn_nocontract(ky, fU0);
    float u0f2 = floorf(su2), v0f2 = floorf(sv2);
    float fu2 = su2 - u0f2, fv2 = sv2 - v0f2;
    int p0 = (int)u0f2 % U0; if (p0 < 0) p0 += U0;
    int q0 = (int)v0f2 % U0; if (q0 < 0) q0 += U0;
    int p1 = p0 + 1; if (p1 >= U0) p1 = 0;
    int q1 = q0 + 1; if (q1 >= U0) q1 = 0;
    int b00 = (p0 * U0 + q0) * 3, b10 = (p1 * U0 + q0) * 3;
    int b01 = (p0 * U0 + q1) * 3, b11 = (p1 * U0 + q1) * 3;
    float omfu2 = 1.0f - fu2, omfv2 = 1.0f - fv2;
    float r0 = (sigmoid_ref(g0[b00+0]) * omfu2 + sigmoid_ref(g0[b10+0]) * fu2) * omfv2
             + (sigmoid_ref(g0[b01+0]) * omfu2 + sigmoid_ref(g0[b11+0]) * fu2) * fv2;
    float r1 = (sigmoid_ref(g0[b00+1]) * omfu2 + sigmoid_ref(g0[b10+1]) * fu2) * omfv2
             + (sigmoid_ref(g0[b01+1]) * omfu2 + sigmoid_ref(g0[b11+1]) * fu2) * fv2;
    float r2 = (sigmoid_ref(g0[b00+2]) * omfu2 + sigmoid_ref(g0[b10+2]) * fu2) * omfv2
             + (sigmoid_ref(g0[b01+2]) * omfu2 + sigmoid_ref(g0[b11+2]) * fu2) * fv2;
    out[3*i+0] = r0; out[3*i+1] = r1; out[3*i+2] = r2;
}

extern "C" void kernel_launch(void* const* d_in, const int* in_sizes, int n_in,
                              void* d_out, int out_size, void* d_ws, size_t ws_size,
                              hipStream_t stream) {
    const float* x  = (const float*)d_in[0];
    const float* g1 = (const float*)d_in[1];
    const float* g0 = (const float*)d_in[2];
    float* out = (float*)d_out;

    int N = in_sizes[0] / 2;
    long long n1 = in_sizes[1];          // U1*U1*2
    long long n0 = in_sizes[2];          // U0*U0*3
    int U1 = (int)(sqrt((double)(n1 / 2)) + 0.5);
    int U0 = (int)(sqrt((double)(n0 / 3)) + 0.5);
    long long ncells1 = (long long)U1 * U1;

    int block = 256;
    size_t need_rowpair = ((size_t)ncells1 * 4 + (size_t)n0) * sizeof(float);
    size_t need_s0      = (size_t)n0 * sizeof(float);

    if (ws_size >= need_rowpair && (n0 % 4) == 0) {
        float* rp = (float*)d_ws;                     // 69.2 MB row-pair raw
        float* s0 = rp + ncells1 * 4;                 // 3.2 MB sigmoided g0
        int n0_4 = (int)(n0 / 4);
        dim3 pgrid((U1 + block - 1) / block, U1);
        rowpair_pack_kernel<<<pgrid, block, 0, stream>>>(g1, rp, U1);
        sigmoid_table_kernel<<<(n0_4 + block - 1) / block, block, 0, stream>>>(
            (const float4*)g0, (float4*)s0, n0_4);
        query_rowpair_kernel<<<(N + block - 1) / block, block, 0, stream>>>(
            x, rp, s0, out, N, U1, U0);
    } else if (ws_size >= need_s0 && (n0 % 4) == 0) {
        float* s0 = (float*)d_ws;                     // 3.2 MB sigmoided g0
        int n0_4 = (int)(n0 / 4);
        sigmoid_table_kernel<<<(n0_4 + block - 1) / block, block, 0, stream>>>(
            (const float4*)g0, (float4*)s0, n0_4);
        query_direct_kernel<<<(N + block - 1) / block, block, 0, stream>>>(
            x, g1, s0, out, N, U1, U0);
    } else {
        query_kernel_fallback<<<(N + block - 1) / block, block, 0, stream>>>(
            x, g1, g0, out, N, U1, U0);
    }
}